// Round 1
// baseline (1386.346 us; speedup 1.0000x reference)
//
#include <hip/hip_runtime.h>
#include <math.h>

#define NN 10000
#define EE 320000
#define ETOT (EE + NN)
#define INC 128
#define HIDC 128
#define OUTC 64
#define NH 3
#define KCL 10
#define SLOPE 0.2f

__device__ __forceinline__ float wave_sum(float v) {
  for (int off = 32; off; off >>= 1) v += __shfl_xor(v, off, 64);
  return v;
}
__device__ __forceinline__ float wave_max(float v) {
  for (int off = 32; off; off >>= 1) v = fmaxf(v, __shfl_xor(v, off, 64));
  return v;
}

// ---------- per-head edge-attr scalar: ce[h] = sum_c We[0,h*C+c]*att_e[h,c] ----------
__global__ __launch_bounds__(64) void ce_kernel(const float* __restrict__ We1,
                                                const float* __restrict__ ae1,
                                                const float* __restrict__ We2,
                                                const float* __restrict__ ae2,
                                                float* __restrict__ ce) {
  int lane = threadIdx.x;
  for (int h = 0; h < NH; h++) {
    float p = 0.f;
    for (int c = lane; c < HIDC; c += 64) p += We1[h * HIDC + c] * ae1[h * HIDC + c];
    p = wave_sum(p);
    if (lane == 0) ce[h] = p;
    float q = 0.f;
    for (int c = lane; c < OUTC; c += 64) q += We2[h * OUTC + c] * ae2[h * OUTC + c];
    q = wave_sum(q);
    if (lane == 0) ce[NH + h] = q;
  }
}

// ---------- CSR build ----------
__global__ __launch_bounds__(256) void csr_count(const int* __restrict__ dst,
                                                 int* __restrict__ counts) {
  int e = blockIdx.x * 256 + threadIdx.x;
  if (e >= ETOT) return;
  int d = (e < EE) ? dst[e] : (e - EE);
  atomicAdd(&counts[d], 1);
}

__global__ __launch_bounds__(1024) void scan_kernel(const int* __restrict__ counts,
                                                    int* __restrict__ offsets) {
  __shared__ int buf[1024];
  __shared__ int carry_s;
  int tid = threadIdx.x;
  if (tid == 0) carry_s = 0;
  __syncthreads();
  for (int base = 0; base < NN; base += 1024) {
    int i = base + tid;
    int v = (i < NN) ? counts[i] : 0;
    buf[tid] = v;
    __syncthreads();
    for (int off = 1; off < 1024; off *= 2) {
      int t = (tid >= off) ? buf[tid - off] : 0;
      __syncthreads();
      buf[tid] += t;
      __syncthreads();
    }
    int c = carry_s;
    if (i < NN) offsets[i + 1] = c + buf[tid];
    __syncthreads();
    if (tid == 0) carry_s = c + buf[1023];
    __syncthreads();
  }
  if (tid == 0) offsets[0] = 0;
}

__global__ __launch_bounds__(256) void csr_fill(const int* __restrict__ dst,
                                                const int* __restrict__ offsets,
                                                int* __restrict__ cursor,
                                                int* __restrict__ edge_ids) {
  int e = blockIdx.x * 256 + threadIdx.x;
  if (e >= ETOT) return;
  int d = (e < EE) ? dst[e] : (e - EE);
  int pos = atomicAdd(&cursor[d], 1);
  edge_ids[offsets[d] + pos] = e;
}

// ---------- node-feature GEMM: C[M,Nc] = A[M,K] @ B[K,Nc]  (no bias) ----------
template <bool NANFIX>
__global__ __launch_bounds__(256) void gemm_nn(const float* __restrict__ A,
                                               const float* __restrict__ B,
                                               float* __restrict__ C,
                                               int M, int K, int Nc) {
  __shared__ float As[16][65];
  __shared__ float Bs[16][65];
  int tid = threadIdx.x;
  int tx = tid & 15, ty = tid >> 4;
  int bm = blockIdx.y * 64, bn = blockIdx.x * 64;
  float acc[4][4] = {};
  for (int k0 = 0; k0 < K; k0 += 16) {
#pragma unroll
    for (int i = 0; i < 4; i++) {
      int idx = tid + i * 256;
      int r = idx >> 4, c = idx & 15;
      float v = (bm + r < M) ? A[(size_t)(bm + r) * K + k0 + c] : 0.f;
      if (NANFIX) v = isnan(v) ? 0.f : v;
      As[c][r] = v;
    }
#pragma unroll
    for (int i = 0; i < 4; i++) {
      int idx = tid + i * 256;
      int r = idx >> 6, c = idx & 63;
      Bs[r][c] = B[(size_t)(k0 + r) * Nc + bn + c];
    }
    __syncthreads();
#pragma unroll
    for (int k = 0; k < 16; k++) {
      float a[4], b[4];
#pragma unroll
      for (int i = 0; i < 4; i++) a[i] = As[k][ty * 4 + i];
#pragma unroll
      for (int j = 0; j < 4; j++) b[j] = Bs[k][tx * 4 + j];
#pragma unroll
      for (int i = 0; i < 4; i++)
#pragma unroll
        for (int j = 0; j < 4; j++) acc[i][j] += a[i] * b[j];
    }
    __syncthreads();
  }
#pragma unroll
  for (int i = 0; i < 4; i++) {
    int r = bm + ty * 4 + i;
    if (r < M) {
#pragma unroll
      for (int j = 0; j < 4; j++) C[(size_t)r * Nc + bn + tx * 4 + j] = acc[i][j];
    }
  }
}

// ---------- per-node attention logits a_s, a_d ----------
template <int C>
__global__ __launch_bounds__(64) void node_aux(const float* __restrict__ hfeat,
                                               const float* __restrict__ att_s,
                                               const float* __restrict__ att_d,
                                               float* __restrict__ a_s,
                                               float* __restrict__ a_d) {
  int n = blockIdx.x, lane = threadIdx.x;
  const float* row = hfeat + (size_t)n * NH * C;
  for (int h = 0; h < NH; h++) {
    float ps = 0.f, pd = 0.f;
    for (int c = lane; c < C; c += 64) {
      float v = row[h * C + c];
      ps += v * att_s[h * C + c];
      pd += v * att_d[h * C + c];
    }
    ps = wave_sum(ps);
    pd = wave_sum(pd);
    if (lane == 0) {
      a_s[n * NH + h] = ps;
      a_d[n * NH + h] = pd;
    }
  }
}

// ---------- fused segment-softmax + aggregation: one wave per dst node ----------
template <int C, bool ELU>
__global__ __launch_bounds__(64) void gat_agg(const float* __restrict__ hfeat,
                                              const float* __restrict__ a_s,
                                              const float* __restrict__ a_d,
                                              const float* __restrict__ ce,
                                              const int* __restrict__ esrc,
                                              const float* __restrict__ ea,
                                              const int* __restrict__ offsets,
                                              const int* __restrict__ edge_ids,
                                              const float* __restrict__ bias,
                                              float* __restrict__ out) {
  const int HC = NH * C;
  const int NACC = HC / 64;
  int n = blockIdx.x, lane = threadIdx.x;
  int beg = offsets[n], end = offsets[n + 1];
  float adn0 = a_d[n * NH + 0], adn1 = a_d[n * NH + 1], adn2 = a_d[n * NH + 2];
  float ce0 = ce[0], ce1v = ce[1], ce2 = ce[2];

  // pass 1: per-head max
  float m0 = -1e30f, m1 = -1e30f, m2 = -1e30f;
  for (int i = beg + lane; i < end; i += 64) {
    int e = edge_ids[i];
    int s;
    float a;
    if (e < EE) { s = esrc[e]; a = ea[e]; } else { s = e - EE; a = 1.f; }
    const float* asr = a_s + NH * s;
    float t0 = asr[0] + adn0 + a * ce0; t0 = t0 > 0.f ? t0 : SLOPE * t0;
    float t1 = asr[1] + adn1 + a * ce1v; t1 = t1 > 0.f ? t1 : SLOPE * t1;
    float t2 = asr[2] + adn2 + a * ce2; t2 = t2 > 0.f ? t2 : SLOPE * t2;
    m0 = fmaxf(m0, t0); m1 = fmaxf(m1, t1); m2 = fmaxf(m2, t2);
  }
  m0 = wave_max(m0); m1 = wave_max(m1); m2 = wave_max(m2);

  // pass 2: per-head sum of exp
  float s0 = 0.f, s1 = 0.f, s2 = 0.f;
  for (int i = beg + lane; i < end; i += 64) {
    int e = edge_ids[i];
    int s;
    float a;
    if (e < EE) { s = esrc[e]; a = ea[e]; } else { s = e - EE; a = 1.f; }
    const float* asr = a_s + NH * s;
    float t0 = asr[0] + adn0 + a * ce0; t0 = t0 > 0.f ? t0 : SLOPE * t0;
    float t1 = asr[1] + adn1 + a * ce1v; t1 = t1 > 0.f ? t1 : SLOPE * t1;
    float t2 = asr[2] + adn2 + a * ce2; t2 = t2 > 0.f ? t2 : SLOPE * t2;
    s0 += expf(t0 - m0); s1 += expf(t1 - m1); s2 += expf(t2 - m2);
  }
  s0 = wave_sum(s0); s1 = wave_sum(s1); s2 = wave_sum(s2);
  float di0 = 1.f / (s0 + 1e-16f), di1 = 1.f / (s1 + 1e-16f), di2 = 1.f / (s2 + 1e-16f);

  // pass 3: weighted aggregation
  __shared__ int sh_src[64];
  __shared__ float sh_c[64][NH];
  float acc[NACC];
#pragma unroll
  for (int k = 0; k < NACC; k++) acc[k] = 0.f;

  for (int base = beg; base < end; base += 64) {
    int i = base + lane;
    if (i < end) {
      int e = edge_ids[i];
      int s;
      float a;
      if (e < EE) { s = esrc[e]; a = ea[e]; } else { s = e - EE; a = 1.f; }
      const float* asr = a_s + NH * s;
      float t0 = asr[0] + adn0 + a * ce0; t0 = t0 > 0.f ? t0 : SLOPE * t0;
      float t1 = asr[1] + adn1 + a * ce1v; t1 = t1 > 0.f ? t1 : SLOPE * t1;
      float t2 = asr[2] + adn2 + a * ce2; t2 = t2 > 0.f ? t2 : SLOPE * t2;
      sh_src[lane] = s;
      sh_c[lane][0] = expf(t0 - m0) * di0;
      sh_c[lane][1] = expf(t1 - m1) * di1;
      sh_c[lane][2] = expf(t2 - m2) * di2;
    }
    __syncthreads();
    int cnt = min(64, end - base);
    for (int t = 0; t < cnt; t++) {
      int s = sh_src[t];
      const float* hr = hfeat + (size_t)s * HC;
#pragma unroll
      for (int k = 0; k < NACC; k++) {
        int j = lane + 64 * k;
        int head = j / C;  // uniform across the wave per k
        acc[k] += hr[j] * sh_c[t][head];
      }
    }
    __syncthreads();
  }
#pragma unroll
  for (int k = 0; k < NACC; k++) {
    int j = lane + 64 * k;
    float v = acc[k] + bias[j];
    if (ELU) v = v > 0.f ? v : expm1f(v);
    out[(size_t)n * HC + j] = v;
  }
}

// ---------- row L2 normalize (C = 192) ----------
__global__ __launch_bounds__(64) void normalize_k(const float* __restrict__ h2,
                                                  float* __restrict__ z) {
  int n = blockIdx.x, lane = threadIdx.x;
  const float* r = h2 + (size_t)n * 192;
  float v0 = r[lane], v1 = r[lane + 64], v2 = r[lane + 128];
  float s = v0 * v0 + v1 * v1 + v2 * v2;
  s = wave_sum(s);
  float inv = 1.f / fmaxf(sqrtf(s), 1e-12f);
  float* zr = z + (size_t)n * 192;
  zr[lane] = v0 * inv;
  zr[lane + 64] = v1 * inv;
  zr[lane + 128] = v2 * inv;
}

// ---------- cluster head: p = softmax(z @ Wp + bp) ----------
__global__ __launch_bounds__(64) void phead(const float* __restrict__ z,
                                            const float* __restrict__ Wp,
                                            const float* __restrict__ bp,
                                            float* __restrict__ p) {
  int n = blockIdx.x, lane = threadIdx.x;
  const float* zr = z + (size_t)n * 192;
  float v0 = zr[lane], v1 = zr[lane + 64], v2 = zr[lane + 128];
  __shared__ float logits[KCL];
  for (int j = 0; j < KCL; j++) {
    float t = v0 * Wp[lane * KCL + j] + v1 * Wp[(lane + 64) * KCL + j] +
              v2 * Wp[(lane + 128) * KCL + j];
    t = wave_sum(t);
    if (lane == 0) logits[j] = t + bp[j];
  }
  __syncthreads();
  if (lane == 0) {
    float m = -1e30f;
    for (int j = 0; j < KCL; j++) m = fmaxf(m, logits[j]);
    float ex[KCL];
    float sum = 0.f;
    for (int j = 0; j < KCL; j++) { ex[j] = expf(logits[j] - m); sum += ex[j]; }
    float inv = 1.f / sum;
    for (int j = 0; j < KCL; j++) p[(size_t)n * KCL + j] = ex[j] * inv;
  }
}

// ---------- A_hat = Z @ Z^T  (fp32, 128x128 tiles, 8x8 per-thread) ----------
__global__ __launch_bounds__(256) void gemm_zzT(const float* __restrict__ Z,
                                                float* __restrict__ C,
                                                int N, int Kd) {
  __shared__ float As[16][132];  // k-major, padded
  __shared__ float Bs[16][132];
  int tid = threadIdx.x;
  int tx = tid & 15, ty = tid >> 4;
  int bm = blockIdx.y * 128, bn = blockIdx.x * 128;
  float acc[8][8] = {};
  for (int k0 = 0; k0 < Kd; k0 += 16) {
#pragma unroll
    for (int i = 0; i < 2; i++) {
      int idx = tid + i * 256;
      int r = idx >> 2, c4 = (idx & 3) * 4;
      float4 va = make_float4(0.f, 0.f, 0.f, 0.f);
      float4 vb = make_float4(0.f, 0.f, 0.f, 0.f);
      if (bm + r < N) va = *(const float4*)(Z + (size_t)(bm + r) * Kd + k0 + c4);
      if (bn + r < N) vb = *(const float4*)(Z + (size_t)(bn + r) * Kd + k0 + c4);
      As[c4 + 0][r] = va.x; As[c4 + 1][r] = va.y; As[c4 + 2][r] = va.z; As[c4 + 3][r] = va.w;
      Bs[c4 + 0][r] = vb.x; Bs[c4 + 1][r] = vb.y; Bs[c4 + 2][r] = vb.z; Bs[c4 + 3][r] = vb.w;
    }
    __syncthreads();
#pragma unroll
    for (int k = 0; k < 16; k++) {
      float4 a0 = *(const float4*)&As[k][ty * 8];
      float4 a1 = *(const float4*)&As[k][ty * 8 + 4];
      float4 b0 = *(const float4*)&Bs[k][tx * 8];
      float4 b1 = *(const float4*)&Bs[k][tx * 8 + 4];
      float av[8] = {a0.x, a0.y, a0.z, a0.w, a1.x, a1.y, a1.z, a1.w};
      float bv[8] = {b0.x, b0.y, b0.z, b0.w, b1.x, b1.y, b1.z, b1.w};
#pragma unroll
      for (int i = 0; i < 8; i++)
#pragma unroll
        for (int j = 0; j < 8; j++) acc[i][j] += av[i] * bv[j];
    }
    __syncthreads();
  }
#pragma unroll
  for (int i = 0; i < 8; i++) {
    int r = bm + ty * 8 + i;
    if (r >= N) continue;
    size_t ro = (size_t)r * N;
    int c0 = bn + tx * 8;
    if (c0 + 8 <= N) {
      *(float4*)&C[ro + c0] = make_float4(acc[i][0], acc[i][1], acc[i][2], acc[i][3]);
      *(float4*)&C[ro + c0 + 4] = make_float4(acc[i][4], acc[i][5], acc[i][6], acc[i][7]);
    } else {
      for (int j = 0; j < 8; j++)
        if (c0 + j < N) C[ro + c0 + j] = acc[i][j];
    }
  }
}

extern "C" void kernel_launch(void* const* d_in, const int* in_sizes, int n_in,
                              void* d_out, int out_size, void* d_ws, size_t ws_size,
                              hipStream_t stream) {
  const float* x = (const float*)d_in[0];
  const int* edge_index = (const int*)d_in[1];
  const float* edge_attr = (const float*)d_in[2];
  const float* W1 = (const float*)d_in[3];
  const float* att_s1 = (const float*)d_in[4];
  const float* att_d1 = (const float*)d_in[5];
  const float* We1 = (const float*)d_in[6];
  const float* att_e1 = (const float*)d_in[7];
  const float* b1 = (const float*)d_in[8];
  const float* W2 = (const float*)d_in[9];
  const float* att_s2 = (const float*)d_in[10];
  const float* att_d2 = (const float*)d_in[11];
  const float* We2 = (const float*)d_in[12];
  const float* att_e2 = (const float*)d_in[13];
  const float* b2 = (const float*)d_in[14];
  const float* Wp = (const float*)d_in[15];
  const float* bp = (const float*)d_in[16];

  const int* esrc = edge_index;        // row 0
  const int* edst = edge_index + EE;   // row 1

  float* A_hat = (float*)d_out;
  float* p_out = A_hat + (size_t)NN * NN;
  float* z_out = p_out + (size_t)NN * KCL;

  // workspace carve
  char* ws = (char*)d_ws;
  float* h1 = (float*)ws;            ws += sizeof(float) * (size_t)NN * 384;
  float* h1act = (float*)ws;         ws += sizeof(float) * (size_t)NN * 384;
  float* as1 = (float*)ws;           ws += sizeof(float) * NN * NH;
  float* ad1 = (float*)ws;           ws += sizeof(float) * NN * NH;
  float* as2 = (float*)ws;           ws += sizeof(float) * NN * NH;
  float* ad2 = (float*)ws;           ws += sizeof(float) * NN * NH;
  float* ce = (float*)ws;            ws += sizeof(float) * 8;
  int* counts = (int*)ws;            ws += sizeof(int) * NN;
  int* cursor = (int*)ws;            ws += sizeof(int) * NN;
  int* offsets = (int*)ws;           ws += sizeof(int) * (NN + 1);
  int* edge_ids = (int*)ws;          ws += sizeof(int) * ETOT;

  // layer-2 feature buffers alias h1 (h1 dead after layer-1 aggregation)
  float* h2 = h1;                 // [NN,192]
  float* h2out = h1 + (size_t)NN * 192;  // [NN,192]

  // zero CSR counters (counts, cursor are adjacent)
  hipMemsetAsync(counts, 0, sizeof(int) * 2 * NN, stream);

  ce_kernel<<<1, 64, 0, stream>>>(We1, att_e1, We2, att_e2, ce);

  int egrid = (ETOT + 255) / 256;
  csr_count<<<egrid, 256, 0, stream>>>(edst, counts);
  scan_kernel<<<1, 1024, 0, stream>>>(counts, offsets);
  csr_fill<<<egrid, 256, 0, stream>>>(edst, offsets, cursor, edge_ids);

  // layer 1: h1 = nan_to_num(x) @ W1   [10000,128]@[128,384]
  gemm_nn<true><<<dim3(384 / 64, (NN + 63) / 64), 256, 0, stream>>>(x, W1, h1, NN, INC, 384);
  node_aux<HIDC><<<NN, 64, 0, stream>>>(h1, att_s1, att_d1, as1, ad1);
  gat_agg<HIDC, true><<<NN, 64, 0, stream>>>(h1, as1, ad1, ce, esrc, edge_attr,
                                             offsets, edge_ids, b1, h1act);

  // layer 2: h2 = h1act @ W2   [10000,384]@[384,192]
  gemm_nn<false><<<dim3(192 / 64, (NN + 63) / 64), 256, 0, stream>>>(h1act, W2, h2, NN, 384, 192);
  node_aux<OUTC><<<NN, 64, 0, stream>>>(h2, att_s2, att_d2, as2, ad2);
  gat_agg<OUTC, false><<<NN, 64, 0, stream>>>(h2, as2, ad2, ce + NH, esrc, edge_attr,
                                              offsets, edge_ids, b2, h2out);

  // z = row-normalize(h2out) -> out
  normalize_k<<<NN, 64, 0, stream>>>(h2out, z_out);

  // p = softmax(z @ Wp + bp) -> out
  phead<<<NN, 64, 0, stream>>>(z_out, Wp, bp, p_out);

  // A_hat = z @ z^T -> out
  gemm_zzT<<<dim3((NN + 127) / 128, (NN + 127) / 128), 256, 0, stream>>>(z_out, A_hat, NN, 192);
}

// Round 2
// 800.070 us; speedup vs baseline: 1.7328x; 1.7328x over previous
//
#include <hip/hip_runtime.h>
#include <hip/hip_bf16.h>
#include <math.h>

#define NN 10000
#define EE 320000
#define ETOT (EE + NN)
#define INC 128
#define HIDC 128
#define OUTC 64
#define NH 3
#define KCL 10
#define SLOPE 0.2f
#define NPAD 10112  // 79*128, padded row count for MFMA tiles

typedef __attribute__((ext_vector_type(8))) short bf16x8;
typedef __attribute__((ext_vector_type(4))) float f32x4;

__device__ __forceinline__ float wave_sum(float v) {
  for (int off = 32; off; off >>= 1) v += __shfl_xor(v, off, 64);
  return v;
}
__device__ __forceinline__ float wave_max(float v) {
  for (int off = 32; off; off >>= 1) v = fmaxf(v, __shfl_xor(v, off, 64));
  return v;
}

// ---------- per-head edge-attr scalar: ce[h] = sum_c We[0,h*C+c]*att_e[h,c] ----------
__global__ __launch_bounds__(64) void ce_kernel(const float* __restrict__ We1,
                                                const float* __restrict__ ae1,
                                                const float* __restrict__ We2,
                                                const float* __restrict__ ae2,
                                                float* __restrict__ ce) {
  int lane = threadIdx.x;
  for (int h = 0; h < NH; h++) {
    float p = 0.f;
    for (int c = lane; c < HIDC; c += 64) p += We1[h * HIDC + c] * ae1[h * HIDC + c];
    p = wave_sum(p);
    if (lane == 0) ce[h] = p;
    float q = 0.f;
    for (int c = lane; c < OUTC; c += 64) q += We2[h * OUTC + c] * ae2[h * OUTC + c];
    q = wave_sum(q);
    if (lane == 0) ce[NH + h] = q;
  }
}

// ---------- CSR build ----------
__global__ __launch_bounds__(256) void csr_count(const int* __restrict__ dst,
                                                 int* __restrict__ counts) {
  int e = blockIdx.x * 256 + threadIdx.x;
  if (e >= ETOT) return;
  int d = (e < EE) ? dst[e] : (e - EE);
  atomicAdd(&counts[d], 1);
}

__global__ __launch_bounds__(1024) void scan_kernel(const int* __restrict__ counts,
                                                    int* __restrict__ offsets) {
  __shared__ int buf[1024];
  __shared__ int carry_s;
  int tid = threadIdx.x;
  if (tid == 0) carry_s = 0;
  __syncthreads();
  for (int base = 0; base < NN; base += 1024) {
    int i = base + tid;
    int v = (i < NN) ? counts[i] : 0;
    buf[tid] = v;
    __syncthreads();
    for (int off = 1; off < 1024; off *= 2) {
      int t = (tid >= off) ? buf[tid - off] : 0;
      __syncthreads();
      buf[tid] += t;
      __syncthreads();
    }
    int c = carry_s;
    if (i < NN) offsets[i + 1] = c + buf[tid];
    __syncthreads();
    if (tid == 0) carry_s = c + buf[1023];
    __syncthreads();
  }
  if (tid == 0) offsets[0] = 0;
}

__global__ __launch_bounds__(256) void csr_fill(const int* __restrict__ dst,
                                                const int* __restrict__ offsets,
                                                int* __restrict__ cursor,
                                                int* __restrict__ edge_ids) {
  int e = blockIdx.x * 256 + threadIdx.x;
  if (e >= ETOT) return;
  int d = (e < EE) ? dst[e] : (e - EE);
  int pos = atomicAdd(&cursor[d], 1);
  edge_ids[offsets[d] + pos] = e;
}

// ---------- node-feature GEMM: C[M,Nc] = A[M,K] @ B[K,Nc]  (no bias) ----------
template <bool NANFIX>
__global__ __launch_bounds__(256) void gemm_nn(const float* __restrict__ A,
                                               const float* __restrict__ B,
                                               float* __restrict__ C,
                                               int M, int K, int Nc) {
  __shared__ float As[16][65];
  __shared__ float Bs[16][65];
  int tid = threadIdx.x;
  int tx = tid & 15, ty = tid >> 4;
  int bm = blockIdx.y * 64, bn = blockIdx.x * 64;
  float acc[4][4] = {};
  for (int k0 = 0; k0 < K; k0 += 16) {
#pragma unroll
    for (int i = 0; i < 4; i++) {
      int idx = tid + i * 256;
      int r = idx >> 4, c = idx & 15;
      float v = (bm + r < M) ? A[(size_t)(bm + r) * K + k0 + c] : 0.f;
      if (NANFIX) v = isnan(v) ? 0.f : v;
      As[c][r] = v;
    }
#pragma unroll
    for (int i = 0; i < 4; i++) {
      int idx = tid + i * 256;
      int r = idx >> 6, c = idx & 63;
      Bs[r][c] = B[(size_t)(k0 + r) * Nc + bn + c];
    }
    __syncthreads();
#pragma unroll
    for (int k = 0; k < 16; k++) {
      float a[4], b[4];
#pragma unroll
      for (int i = 0; i < 4; i++) a[i] = As[k][ty * 4 + i];
#pragma unroll
      for (int j = 0; j < 4; j++) b[j] = Bs[k][tx * 4 + j];
#pragma unroll
      for (int i = 0; i < 4; i++)
#pragma unroll
        for (int j = 0; j < 4; j++) acc[i][j] += a[i] * b[j];
    }
    __syncthreads();
  }
#pragma unroll
  for (int i = 0; i < 4; i++) {
    int r = bm + ty * 4 + i;
    if (r < M) {
#pragma unroll
      for (int j = 0; j < 4; j++) C[(size_t)r * Nc + bn + tx * 4 + j] = acc[i][j];
    }
  }
}

// ---------- per-node attention logits a_s, a_d ----------
template <int C>
__global__ __launch_bounds__(64) void node_aux(const float* __restrict__ hfeat,
                                               const float* __restrict__ att_s,
                                               const float* __restrict__ att_d,
                                               float* __restrict__ a_s,
                                               float* __restrict__ a_d) {
  int n = blockIdx.x, lane = threadIdx.x;
  const float* row = hfeat + (size_t)n * NH * C;
  for (int h = 0; h < NH; h++) {
    float ps = 0.f, pd = 0.f;
    for (int c = lane; c < C; c += 64) {
      float v = row[h * C + c];
      ps += v * att_s[h * C + c];
      pd += v * att_d[h * C + c];
    }
    ps = wave_sum(ps);
    pd = wave_sum(pd);
    if (lane == 0) {
      a_s[n * NH + h] = ps;
      a_d[n * NH + h] = pd;
    }
  }
}

// ---------- fused segment-softmax + aggregation: one wave per dst node ----------
template <int C, bool ELU>
__global__ __launch_bounds__(64) void gat_agg(const float* __restrict__ hfeat,
                                              const float* __restrict__ a_s,
                                              const float* __restrict__ a_d,
                                              const float* __restrict__ ce,
                                              const int* __restrict__ esrc,
                                              const float* __restrict__ ea,
                                              const int* __restrict__ offsets,
                                              const int* __restrict__ edge_ids,
                                              const float* __restrict__ bias,
                                              float* __restrict__ out) {
  const int HC = NH * C;
  const int NACC = HC / 64;
  int n = blockIdx.x, lane = threadIdx.x;
  int beg = offsets[n], end = offsets[n + 1];
  float adn0 = a_d[n * NH + 0], adn1 = a_d[n * NH + 1], adn2 = a_d[n * NH + 2];
  float ce0 = ce[0], ce1v = ce[1], ce2 = ce[2];

  // pass 1: per-head max
  float m0 = -1e30f, m1 = -1e30f, m2 = -1e30f;
  for (int i = beg + lane; i < end; i += 64) {
    int e = edge_ids[i];
    int s;
    float a;
    if (e < EE) { s = esrc[e]; a = ea[e]; } else { s = e - EE; a = 1.f; }
    const float* asr = a_s + NH * s;
    float t0 = asr[0] + adn0 + a * ce0; t0 = t0 > 0.f ? t0 : SLOPE * t0;
    float t1 = asr[1] + adn1 + a * ce1v; t1 = t1 > 0.f ? t1 : SLOPE * t1;
    float t2 = asr[2] + adn2 + a * ce2; t2 = t2 > 0.f ? t2 : SLOPE * t2;
    m0 = fmaxf(m0, t0); m1 = fmaxf(m1, t1); m2 = fmaxf(m2, t2);
  }
  m0 = wave_max(m0); m1 = wave_max(m1); m2 = wave_max(m2);

  // pass 2: per-head sum of exp
  float s0 = 0.f, s1 = 0.f, s2 = 0.f;
  for (int i = beg + lane; i < end; i += 64) {
    int e = edge_ids[i];
    int s;
    float a;
    if (e < EE) { s = esrc[e]; a = ea[e]; } else { s = e - EE; a = 1.f; }
    const float* asr = a_s + NH * s;
    float t0 = asr[0] + adn0 + a * ce0; t0 = t0 > 0.f ? t0 : SLOPE * t0;
    float t1 = asr[1] + adn1 + a * ce1v; t1 = t1 > 0.f ? t1 : SLOPE * t1;
    float t2 = asr[2] + adn2 + a * ce2; t2 = t2 > 0.f ? t2 : SLOPE * t2;
    s0 += expf(t0 - m0); s1 += expf(t1 - m1); s2 += expf(t2 - m2);
  }
  s0 = wave_sum(s0); s1 = wave_sum(s1); s2 = wave_sum(s2);
  float di0 = 1.f / (s0 + 1e-16f), di1 = 1.f / (s1 + 1e-16f), di2 = 1.f / (s2 + 1e-16f);

  // pass 3: weighted aggregation
  __shared__ int sh_src[64];
  __shared__ float sh_c[64][NH];
  float acc[NACC];
#pragma unroll
  for (int k = 0; k < NACC; k++) acc[k] = 0.f;

  for (int base = beg; base < end; base += 64) {
    int i = base + lane;
    if (i < end) {
      int e = edge_ids[i];
      int s;
      float a;
      if (e < EE) { s = esrc[e]; a = ea[e]; } else { s = e - EE; a = 1.f; }
      const float* asr = a_s + NH * s;
      float t0 = asr[0] + adn0 + a * ce0; t0 = t0 > 0.f ? t0 : SLOPE * t0;
      float t1 = asr[1] + adn1 + a * ce1v; t1 = t1 > 0.f ? t1 : SLOPE * t1;
      float t2 = asr[2] + adn2 + a * ce2; t2 = t2 > 0.f ? t2 : SLOPE * t2;
      sh_src[lane] = s;
      sh_c[lane][0] = expf(t0 - m0) * di0;
      sh_c[lane][1] = expf(t1 - m1) * di1;
      sh_c[lane][2] = expf(t2 - m2) * di2;
    }
    __syncthreads();
    int cnt = min(64, end - base);
    for (int t = 0; t < cnt; t++) {
      int s = sh_src[t];
      const float* hr = hfeat + (size_t)s * HC;
#pragma unroll
      for (int k = 0; k < NACC; k++) {
        int j = lane + 64 * k;
        int head = j / C;  // uniform across the wave per k
        acc[k] += hr[j] * sh_c[t][head];
      }
    }
    __syncthreads();
  }
#pragma unroll
  for (int k = 0; k < NACC; k++) {
    int j = lane + 64 * k;
    float v = acc[k] + bias[j];
    if (ELU) v = v > 0.f ? v : expm1f(v);
    out[(size_t)n * HC + j] = v;
  }
}

// ---------- row L2 normalize (C = 192), fp32 out + bf16 copy for MFMA ----------
__global__ __launch_bounds__(64) void normalize_k(const float* __restrict__ h2,
                                                  float* __restrict__ z,
                                                  __hip_bfloat16* __restrict__ zb) {
  int n = blockIdx.x, lane = threadIdx.x;
  const float* r = h2 + (size_t)n * 192;
  float v0 = r[lane], v1 = r[lane + 64], v2 = r[lane + 128];
  float s = v0 * v0 + v1 * v1 + v2 * v2;
  s = wave_sum(s);
  float inv = 1.f / fmaxf(sqrtf(s), 1e-12f);
  v0 *= inv; v1 *= inv; v2 *= inv;
  float* zr = z + (size_t)n * 192;
  zr[lane] = v0;
  zr[lane + 64] = v1;
  zr[lane + 128] = v2;
  __hip_bfloat16* zbr = zb + (size_t)n * 192;
  zbr[lane] = __float2bfloat16(v0);
  zbr[lane + 64] = __float2bfloat16(v1);
  zbr[lane + 128] = __float2bfloat16(v2);
}

// ---------- cluster head: p = softmax(z @ Wp + bp) ----------
__global__ __launch_bounds__(64) void phead(const float* __restrict__ z,
                                            const float* __restrict__ Wp,
                                            const float* __restrict__ bp,
                                            float* __restrict__ p) {
  int n = blockIdx.x, lane = threadIdx.x;
  const float* zr = z + (size_t)n * 192;
  float v0 = zr[lane], v1 = zr[lane + 64], v2 = zr[lane + 128];
  __shared__ float logits[KCL];
  for (int j = 0; j < KCL; j++) {
    float t = v0 * Wp[lane * KCL + j] + v1 * Wp[(lane + 64) * KCL + j] +
              v2 * Wp[(lane + 128) * KCL + j];
    t = wave_sum(t);
    if (lane == 0) logits[j] = t + bp[j];
  }
  __syncthreads();
  if (lane == 0) {
    float m = -1e30f;
    for (int j = 0; j < KCL; j++) m = fmaxf(m, logits[j]);
    float ex[KCL];
    float sum = 0.f;
    for (int j = 0; j < KCL; j++) { ex[j] = expf(logits[j] - m); sum += ex[j]; }
    float inv = 1.f / sum;
    for (int j = 0; j < KCL; j++) p[(size_t)n * KCL + j] = ex[j] * inv;
  }
}

// ---------- A_hat = Zb @ Zb^T via bf16 MFMA ----------
// 128x128 tile / block, 4 waves in 2x2, each wave 4x4 grid of 16x16x32 MFMA.
// global_load_lds width-16 staging; K = 192 = 6 * 32.
__global__ __launch_bounds__(256) void gemm_zzT_mfma(const short* __restrict__ Zb,
                                                     float* __restrict__ C, int N) {
  __shared__ short As[128 * 32];
  __shared__ short Bs[128 * 32];
  int tid = threadIdx.x;
  int lane = tid & 63;
  int wave = tid >> 6;
  int wm = (wave >> 1) * 64, wn = (wave & 1) * 64;
  int bm = blockIdx.y * 128, bn = blockIdx.x * 128;

  f32x4 acc[4][4] = {};

  int lrow = tid >> 2;        // 0..63
  int lcol = (tid & 3) * 8;   // 0,8,16,24  (elements)

  int fr = lane & 15;         // fragment row/col within 16
  int fk = (lane >> 4) * 8;   // fragment k offset

  for (int kt = 0; kt < 6; kt++) {
    int k0 = kt * 32;
    const short* ga0 = Zb + (size_t)(bm + lrow) * 192 + k0 + lcol;
    const short* ga1 = Zb + (size_t)(bm + 64 + lrow) * 192 + k0 + lcol;
    const short* gb0 = Zb + (size_t)(bn + lrow) * 192 + k0 + lcol;
    const short* gb1 = Zb + (size_t)(bn + 64 + lrow) * 192 + k0 + lcol;
    __builtin_amdgcn_global_load_lds(
        (const __attribute__((address_space(1))) unsigned int*)ga0,
        (__attribute__((address_space(3))) unsigned int*)&As[lrow * 32 + lcol], 16, 0, 0);
    __builtin_amdgcn_global_load_lds(
        (const __attribute__((address_space(1))) unsigned int*)ga1,
        (__attribute__((address_space(3))) unsigned int*)&As[(64 + lrow) * 32 + lcol], 16, 0, 0);
    __builtin_amdgcn_global_load_lds(
        (const __attribute__((address_space(1))) unsigned int*)gb0,
        (__attribute__((address_space(3))) unsigned int*)&Bs[lrow * 32 + lcol], 16, 0, 0);
    __builtin_amdgcn_global_load_lds(
        (const __attribute__((address_space(1))) unsigned int*)gb1,
        (__attribute__((address_space(3))) unsigned int*)&Bs[(64 + lrow) * 32 + lcol], 16, 0, 0);
    __syncthreads();

    bf16x8 af[4], bfr[4];
#pragma unroll
    for (int t = 0; t < 4; t++) af[t] = *(const bf16x8*)&As[(wm + t * 16 + fr) * 32 + fk];
#pragma unroll
    for (int t = 0; t < 4; t++) bfr[t] = *(const bf16x8*)&Bs[(wn + t * 16 + fr) * 32 + fk];
#pragma unroll
    for (int i = 0; i < 4; i++)
#pragma unroll
      for (int j = 0; j < 4; j++)
        acc[i][j] = __builtin_amdgcn_mfma_f32_16x16x32_bf16(af[i], bfr[j], acc[i][j], 0, 0, 0);
    __syncthreads();
  }

  // store: C/D layout col = lane&15, row = (lane>>4)*4 + reg
  int col0 = lane & 15;
  int rquad = (lane >> 4) * 4;
#pragma unroll
  for (int i = 0; i < 4; i++) {
#pragma unroll
    for (int v = 0; v < 4; v++) {
      int r = bm + wm + i * 16 + rquad + v;
      if (r >= N) continue;
      size_t ro = (size_t)r * N;
#pragma unroll
      for (int j = 0; j < 4; j++) {
        int c = bn + wn + j * 16 + col0;
        if (c < N) C[ro + c] = acc[i][j][v];
      }
    }
  }
}

extern "C" void kernel_launch(void* const* d_in, const int* in_sizes, int n_in,
                              void* d_out, int out_size, void* d_ws, size_t ws_size,
                              hipStream_t stream) {
  const float* x = (const float*)d_in[0];
  const int* edge_index = (const int*)d_in[1];
  const float* edge_attr = (const float*)d_in[2];
  const float* W1 = (const float*)d_in[3];
  const float* att_s1 = (const float*)d_in[4];
  const float* att_d1 = (const float*)d_in[5];
  const float* We1 = (const float*)d_in[6];
  const float* att_e1 = (const float*)d_in[7];
  const float* b1 = (const float*)d_in[8];
  const float* W2 = (const float*)d_in[9];
  const float* att_s2 = (const float*)d_in[10];
  const float* att_d2 = (const float*)d_in[11];
  const float* We2 = (const float*)d_in[12];
  const float* att_e2 = (const float*)d_in[13];
  const float* b2 = (const float*)d_in[14];
  const float* Wp = (const float*)d_in[15];
  const float* bp = (const float*)d_in[16];

  const int* esrc = edge_index;        // row 0
  const int* edst = edge_index + EE;   // row 1

  float* A_hat = (float*)d_out;
  float* p_out = A_hat + (size_t)NN * NN;
  float* z_out = p_out + (size_t)NN * KCL;

  // workspace carve
  char* ws = (char*)d_ws;
  float* h1 = (float*)ws;            ws += sizeof(float) * (size_t)NN * 384;
  float* h1act = (float*)ws;         ws += sizeof(float) * (size_t)NN * 384;
  float* as1 = (float*)ws;           ws += sizeof(float) * NN * NH;
  float* ad1 = (float*)ws;           ws += sizeof(float) * NN * NH;
  float* as2 = (float*)ws;           ws += sizeof(float) * NN * NH;
  float* ad2 = (float*)ws;           ws += sizeof(float) * NN * NH;
  float* ce = (float*)ws;            ws += sizeof(float) * 8;
  int* counts = (int*)ws;            ws += sizeof(int) * NN;
  int* cursor = (int*)ws;            ws += sizeof(int) * NN;
  int* offsets = (int*)ws;           ws += sizeof(int) * (NN + 1);
  int* edge_ids = (int*)ws;          ws += sizeof(int) * ETOT;
  __hip_bfloat16* zb = (__hip_bfloat16*)ws; ws += sizeof(__hip_bfloat16) * (size_t)NPAD * 192;

  // layer-2 feature buffers alias h1 (h1 dead after layer-1 aggregation)
  float* h2 = h1;                        // [NN,192]
  float* h2out = h1 + (size_t)NN * 192;  // [NN,192]

  // zero CSR counters (counts, cursor are adjacent)
  hipMemsetAsync(counts, 0, sizeof(int) * 2 * NN, stream);

  ce_kernel<<<1, 64, 0, stream>>>(We1, att_e1, We2, att_e2, ce);

  int egrid = (ETOT + 255) / 256;
  csr_count<<<egrid, 256, 0, stream>>>(edst, counts);
  scan_kernel<<<1, 1024, 0, stream>>>(counts, offsets);
  csr_fill<<<egrid, 256, 0, stream>>>(edst, offsets, cursor, edge_ids);

  // layer 1: h1 = nan_to_num(x) @ W1   [10000,128]@[128,384]
  gemm_nn<true><<<dim3(384 / 64, (NN + 63) / 64), 256, 0, stream>>>(x, W1, h1, NN, INC, 384);
  node_aux<HIDC><<<NN, 64, 0, stream>>>(h1, att_s1, att_d1, as1, ad1);
  gat_agg<HIDC, true><<<NN, 64, 0, stream>>>(h1, as1, ad1, ce, esrc, edge_attr,
                                             offsets, edge_ids, b1, h1act);

  // layer 2: h2 = h1act @ W2   [10000,384]@[384,192]
  gemm_nn<false><<<dim3(192 / 64, (NN + 63) / 64), 256, 0, stream>>>(h1act, W2, h2, NN, 384, 192);
  node_aux<OUTC><<<NN, 64, 0, stream>>>(h2, att_s2, att_d2, as2, ad2);
  gat_agg<OUTC, false><<<NN, 64, 0, stream>>>(h2, as2, ad2, ce + NH, esrc, edge_attr,
                                              offsets, edge_ids, b2, h2out);

  // z = row-normalize(h2out) -> out (fp32) + zb (bf16, padded for MFMA tiles)
  normalize_k<<<NN, 64, 0, stream>>>(h2out, z_out, zb);

  // p = softmax(z @ Wp + bp) -> out
  phead<<<NN, 64, 0, stream>>>(z_out, Wp, bp, p_out);

  // A_hat = zb @ zb^T -> out (bf16 MFMA, fp32 accumulate)
  gemm_zzT_mfma<<<dim3((NN + 127) / 128, (NN + 127) / 128), 256, 0, stream>>>(
      (const short*)zb, A_hat, NN);
}